// Round 15
// baseline (424.725 us; speedup 1.0000x reference)
//
#include <hip/hip_runtime.h>
#include <hip/hip_fp16.h>
#include <math.h>

#define NU 100000
#define NI 50000
#define NENT 80000
#define NN 180000
#define NEDGE 800000
#define NB (3 * NU + NENT)             // 380000 class-partitioned buckets
#define SCAN_NB ((NB + 1023) / 1024)   // 372
#define UFIN_BLKS ((NU + 63) / 64)     // 1563
#define EFIN_BLKS (NENT / 64)          // 1250
#define NODE_BLKS ((NN / 16 + 3) / 4)  // 2813

typedef _Float16 f16x4 __attribute__((ext_vector_type(4)));
typedef _Float16 f16x2 __attribute__((ext_vector_type(2)));
typedef float f32x4 __attribute__((ext_vector_type(4)));

__device__ __forceinline__ float sigmoid_f(float x) { return 1.0f / (1.0f + __expf(-x)); }
__device__ __forceinline__ unsigned pack2(float a, float b) {
    __half2 h = __floats2half2_rn(a, b);
    return *(unsigned*)&h;
}
__device__ __forceinline__ f16x2 u2h2(unsigned u) { union { unsigned u; f16x2 h; } x; x.u = u; return x.h; }
__device__ __forceinline__ float fdot2f(f16x2 a, f16x2 b, float c) {
#if __has_builtin(__builtin_amdgcn_fdot2)
    return __builtin_amdgcn_fdot2(a, b, c, false);
#else
    return (float)a[0] * (float)b[0] + (float)a[1] * (float)b[1] + c;
#endif
}
__device__ __forceinline__ _Float16 hminf(_Float16 a, _Float16 b) { return a < b ? a : b; }
__device__ __forceinline__ _Float16 hmaxf(_Float16 a, _Float16 b) { return a > b ? a : b; }

template<typename T>
__device__ __forceinline__ f16x4 ldfrag(const T* __restrict__ p) {
    if constexpr (sizeof(T) == 2) {
        return *(const f16x4*)p;
    } else {
        float4 v = *(const float4*)p;
        f16x4 r; r[0] = (_Float16)v.x; r[1] = (_Float16)v.y; r[2] = (_Float16)v.z; r[3] = (_Float16)v.w;
        return r;
    }
}
template<typename T>
__device__ __forceinline__ f16x4 ldfragr(const T* __restrict__ p) {   // relu before/after cvt
    if constexpr (sizeof(T) == 2) {
        f16x4 v = *(const f16x4*)p;
        #pragma unroll
        for (int i = 0; i < 4; ++i) v[i] = hmaxf(v[i], (_Float16)0.f);
        return v;
    } else {
        float4 v = *(const float4*)p;
        f16x4 r;
        r[0] = (_Float16)fmaxf(v.x, 0.f); r[1] = (_Float16)fmaxf(v.y, 0.f);
        r[2] = (_Float16)fmaxf(v.z, 0.f); r[3] = (_Float16)fmaxf(v.w, 0.f);
        return r;
    }
}
__device__ __forceinline__ f16x4 fragp(const _Float16* __restrict__ Wp, int dt, int ks, int lane) {
    return *(const f16x4*)(Wp + (((dt * 4 + ks) * 64 + lane) << 2));
}
// swapped-operand MFMA: D'[dim][node] = W x ; chaining needs no transpose
__device__ __forceinline__ f32x4 mmw(f16x4 wfrag, f16x4 xfrag, f32x4 c) {
    return __builtin_amdgcn_mfma_f32_16x16x16f16(wfrag, xfrag, c, 0, 0, 0);
}
__device__ __forceinline__ f32x4 bias4(const float* __restrict__ b, int dt, int lk) {
    float4 v = *(const float4*)(b + dt * 16 + lk * 4);
    f32x4 r = {v.x, v.y, v.z, v.w};
    return r;
}
// class bucket: user heads split by tail class; ent heads single bucket
__device__ __forceinline__ int bucket_of(int h, int t) {
    if (h < NU) return h * 3 + ((t < NU) ? 0 : (t < NU + NI) ? 1 : 2);
    return 3 * NU + (h - NU);
}

// ---------------- weight prepack + counts zero (one launch) ----------------
__global__ __launch_bounds__(256) void prep_zero(
    const float* __restrict__ W0, const float* __restrict__ W1,
    const float* __restrict__ W2, const float* __restrict__ W3,
    _Float16* __restrict__ out, int* __restrict__ counts)
{
    int idx = blockIdx.x * 256 + threadIdx.x;
    if (idx < 16384) {
        int mat = idx >> 12, wi = idx & 4095;
        const float* W = (mat == 0) ? W0 : (mat == 1) ? W1 : (mat == 2) ? W2 : W3;
        int tile = wi >> 8;
        int dt = tile >> 2, ks = tile & 3;
        int ln = (wi >> 2) & 63, j = wi & 3;
        int lr = ln & 15, lk = ln >> 4;
        out[idx] = (_Float16)W[(size_t)(dt * 16 + lr) * 64 + ks * 16 + lk * 4 + j];
    }
    int z = idx - 16384;
    if (z >= 0 && z < NB) counts[z] = 0;
}

// ---------------- node pass: swapped MFMA, zero LDS ----------------
template<typename T>
__global__ __launch_bounds__(256) void node_pass(
    const T* __restrict__ embU, const T* __restrict__ embE,
    const T* __restrict__ offU, const T* __restrict__ offE,
    const _Float16* __restrict__ cW1f, const float* __restrict__ cb1,
    const _Float16* __restrict__ cW2f, const float* __restrict__ cb2,
    const _Float16* __restrict__ oW1f, const float* __restrict__ ob1,
    unsigned* __restrict__ packedA, unsigned* __restrict__ packedB)
{
    int lane = threadIdx.x & 63, wid = threadIdx.x >> 6;
    int n0 = (blockIdx.x * 4 + wid) * 16;
    if (n0 >= NN) return;
    int lr = lane & 15, lk = lane >> 4;
    const T* eb; const T* ob;
    if (n0 < NU) { eb = embU + (size_t)n0 * 64; ob = offU + (size_t)n0 * 64; }
    else         { eb = embE + (size_t)(n0 - NU) * 64; ob = offE + (size_t)(n0 - NU) * 64; }

    f16x4 ax[4], axo[4];
    #pragma unroll
    for (int ks = 0; ks < 4; ++ks) {
        ax[ks]  = ldfrag(eb + (size_t)lr * 64 + ks * 16 + lk * 4);
        axo[ks] = ldfragr(ob + (size_t)lr * 64 + ks * 16 + lk * 4);
    }
    f32x4 a1c[4];
    #pragma unroll
    for (int dt = 0; dt < 4; ++dt) {
        f32x4 c = bias4(cb1, dt, lk);
        #pragma unroll
        for (int ks = 0; ks < 4; ++ks) c = mmw(fragp(cW1f, dt, ks, lane), ax[ks], c);
        a1c[dt] = c;
    }
    f16x4 a1f[4];
    #pragma unroll
    for (int ks = 0; ks < 4; ++ks)
        #pragma unroll
        for (int r = 0; r < 4; ++r) a1f[ks][r] = (_Float16)fmaxf(a1c[ks][r], 0.f);
    f32x4 lg[4];
    #pragma unroll
    for (int dt = 0; dt < 4; ++dt) {
        f32x4 c = bias4(cb2, dt, lk);
        #pragma unroll
        for (int ks = 0; ks < 4; ++ks) c = mmw(fragp(cW2f, dt, ks, lane), a1f[ks], c);
        lg[dt] = c;
    }
    f32x4 ao[4];
    #pragma unroll
    for (int dt = 0; dt < 4; ++dt) {
        f32x4 c = bias4(ob1, dt, lk);
        #pragma unroll
        for (int ks = 0; ks < 4; ++ks) c = mmw(fragp(oW1f, dt, ks, lane), axo[ks], c);
        ao[dt] = c;
    }
    #pragma unroll
    for (int dt = 0; dt < 4; ++dt) {
        uint4 ua, ub;
        unsigned* pa = &ua.x; unsigned* pb = &ub.x;
        #pragma unroll
        for (int r = 0; r < 4; ++r) {
            float ev = __expf(lg[dt][r]);   // segment-max shift skipped: |lg| << 1
            pa[r] = pack2(ev, ev * (float)ax[dt][r]);
            pb[r] = pack2(fmaxf(ao[dt][r], 0.f), (float)axo[dt][r]);
        }
        size_t idx = (size_t)(n0 + lr) * 64 + dt * 16 + lk * 4;
        *(uint4*)(packedA + idx) = ua;
        *(uint4*)(packedB + idx) = ub;
    }
}

// ---------------- CSR build (class-partitioned buckets) ----------------
__global__ __launch_bounds__(256) void hist_k(const int* __restrict__ head, const int* __restrict__ tail,
                                              int* __restrict__ counts) {
    int e = blockIdx.x * 256 + threadIdx.x;
    if (e < NEDGE) atomicAdd(&counts[bucket_of(head[e], tail[e])], 1);
}

__global__ __launch_bounds__(1024) void scan_local(const int* __restrict__ counts,
                                                   int* __restrict__ excl, int* __restrict__ partials) {
    __shared__ int wsum[16];
    int tid = threadIdx.x, lane = tid & 63, wid = tid >> 6;
    int i = blockIdx.x * 1024 + tid;
    int v = (i < NB) ? counts[i] : 0;
    int s = v;
    #pragma unroll
    for (int d = 1; d < 64; d <<= 1) { int u = __shfl_up(s, d, 64); if (lane >= d) s += u; }
    if (lane == 63) wsum[wid] = s;
    __syncthreads();
    if (wid == 0 && lane < 16) {
        int w = wsum[lane];
        #pragma unroll
        for (int d = 1; d < 16; d <<= 1) { int u = __shfl_up(w, d, 64); if (lane >= d) w += u; }
        wsum[lane] = w;
    }
    __syncthreads();
    int base = wid ? wsum[wid - 1] : 0;
    if (i < NB) excl[i] = base + s - v;
    if (tid == 1023) partials[blockIdx.x] = wsum[15];
}

__global__ __launch_bounds__(1024) void scan_carry(const int* __restrict__ partials, int* __restrict__ carries) {
    __shared__ int wsum[16];
    int tid = threadIdx.x, lane = tid & 63, wid = tid >> 6;
    int v = (tid < SCAN_NB) ? partials[tid] : 0;
    int s = v;
    #pragma unroll
    for (int d = 1; d < 64; d <<= 1) { int u = __shfl_up(s, d, 64); if (lane >= d) s += u; }
    if (lane == 63) wsum[wid] = s;
    __syncthreads();
    if (wid == 0 && lane < 16) {
        int w = wsum[lane];
        #pragma unroll
        for (int d = 1; d < 16; d <<= 1) { int u = __shfl_up(w, d, 64); if (lane >= d) w += u; }
        wsum[lane] = w;
    }
    __syncthreads();
    int base = wid ? wsum[wid - 1] : 0;
    if (tid < SCAN_NB) carries[tid] = base + s - v;
}

__global__ __launch_bounds__(1024) void scan_add(int* __restrict__ excl, const int* __restrict__ carries,
                                                 int* __restrict__ cursor) {
    int i = blockIdx.x * 1024 + threadIdx.x;
    if (i < NB) { int o = excl[i] + carries[blockIdx.x]; excl[i] = o; cursor[i] = o; }
    if (i == 0) excl[NB] = NEDGE;
}

// stores PRE-SHIFTED byte-row offsets (tail<<8)
__global__ __launch_bounds__(256) void scatter_k(const int* __restrict__ head, const int* __restrict__ tail,
                                                 int* __restrict__ cursor, int* __restrict__ sorted_t) {
    int e = blockIdx.x * 256 + threadIdx.x;
    if (e < NEDGE) {
        int pos = atomicAdd(&cursor[bucket_of(head[e], tail[e])], 1);
        sorted_t[pos] = tail[e] << 8;
    }
}

// ---------------- branch-free segment runner: CLS 0 = center only; 1 = +min; 2 = +max ----
template<int CLS>
__device__ __forceinline__ void run_seg(
    const char* __restrict__ pA, const char* __restrict__ pB,
    const int* __restrict__ sorted_t, int beg, int end, int loff, int lane,
    float& den, float& num, float& s, _Float16& m)
{
    const f16x2 SEL_LO = {(_Float16)1.0f, (_Float16)0.0f};
    const f16x2 SEL_HI = {(_Float16)0.0f, (_Float16)1.0f};
#define LOADQ(toff, a, b)                                                       \
    do {                                                                        \
        a = *(const unsigned*)(pA + (size_t)(unsigned)(toff) + loff);           \
        if (CLS) b = *(const unsigned*)(pB + (size_t)(unsigned)(toff) + loff);  \
    } while (0)
#define CONSUME(qa, qb)                                                         \
    do {                                                                        \
        f16x2 ea = u2h2(qa);                                                    \
        den = fdot2f(ea, SEL_LO, den);                                          \
        num = fdot2f(ea, SEL_HI, num);                                          \
        if (CLS) {                                                              \
            f16x2 ab = u2h2(qb);                                                \
            s = fdot2f(ab, SEL_LO, s);                                          \
            m = (CLS == 1) ? hminf(m, ab[1]) : hmaxf(m, ab[1]);                 \
        }                                                                       \
    } while (0)
    for (int base = beg; base < end; base += 64) {
        int rem = end - base; if (rem > 64) rem = 64;
        int tv = sorted_t[base + (lane < rem ? lane : 0)];
        int tA, tB; unsigned aA = 0, aB = 0, bA = 0, bB = 0;
        tA = __builtin_amdgcn_readlane(tv, 0);
        LOADQ(tA, aA, bA);
        if (rem > 1) { tB = __builtin_amdgcn_readlane(tv, 1); LOADQ(tB, aB, bB); }
        int j = 0;
        for (; j + 2 <= rem; j += 2) {
            CONSUME(aA, bA);
            if (j + 2 < rem) { tA = __builtin_amdgcn_readlane(tv, j + 2); LOADQ(tA, aA, bA); }
            CONSUME(aB, bB);
            if (j + 3 < rem) { tB = __builtin_amdgcn_readlane(tv, j + 3); LOADQ(tB, aB, bB); }
        }
        if (j < rem) CONSUME(aA, bA);   // odd tail
    }
#undef LOADQ
#undef CONSUME
}

// ---------------- segment pass: one wave per head; class-partitioned sub-loops ----------
template<bool OUT16>
__global__ __launch_bounds__(256) void seg_pass(
    const unsigned* __restrict__ packedA, const unsigned* __restrict__ packedB,
    const int* __restrict__ offsets, const int* __restrict__ sorted_t,
    void* __restrict__ embOutU_, void* __restrict__ embOutE_,
    _Float16* __restrict__ meanI, _Float16* __restrict__ redI,
    _Float16* __restrict__ meanU, _Float16* __restrict__ redU,
    _Float16* __restrict__ meanE, _Float16* __restrict__ redE)
{
    int lane = threadIdx.x & 63;
    int h = blockIdx.x * 4 + (threadIdx.x >> 6);    // NN % 4 == 0
    bool isUser = (h < NU);
    bool entMin = (h >= NU + NI);
    float num = 0.f, den = 0.f, s_i = 0.f, s_u = 0.f;
    const _Float16 HINF = u2h2(0x7C007C00u)[0];
    _Float16 m_i = (isUser || entMin) ? HINF : (_Float16)0.f;
    _Float16 m_u = (_Float16)0.f;
    float c_i, c_u = 0.f;

    const char* pA = (const char*)packedA;
    const char* pB = (const char*)packedB;
    int loff = lane << 2;

    if (isUser) {
        int o0 = offsets[3 * h], o1 = offsets[3 * h + 1];
        int o2 = offsets[3 * h + 2], o3 = offsets[3 * h + 3];
        run_seg<0>(pA, pB, sorted_t, o0, o1, loff, lane, den, num, s_i, m_i);
        run_seg<1>(pA, pB, sorted_t, o1, o2, loff, lane, den, num, s_i, m_i);
        run_seg<2>(pA, pB, sorted_t, o2, o3, loff, lane, den, num, s_u, m_u);
        c_i = (float)(o2 - o1); c_u = (float)(o3 - o2);
    } else {
        int b = 3 * NU + (h - NU);
        int o0 = offsets[b], o1 = offsets[b + 1];
        if (entMin) run_seg<1>(pA, pB, sorted_t, o0, o1, loff, lane, den, num, s_i, m_i);
        else        run_seg<2>(pA, pB, sorted_t, o0, o1, loff, lane, den, num, s_i, m_i);
        c_i = (float)(o1 - o0);
    }

    // center: softmax-weighted mean + row L2 normalize
    float v = (den > 0.f) ? num / den : 0.f;
    float sq = v * v;
    #pragma unroll
    for (int m = 32; m; m >>= 1) sq += __shfl_xor(sq, m, 64);
    v = v / fmaxf(sqrtf(sq), 1e-12f);

    float m_if = (float)m_i;
    if (m_if > 1e37f) m_if = 0.f;                   // empty min-segment -> 0
    float rc_i = __builtin_amdgcn_rcpf(fmaxf(c_i, 1.f));
    if (isUser) {
        size_t r = (size_t)h * 64 + lane;
        if constexpr (OUT16) ((_Float16*)embOutU_)[r] = (_Float16)v;
        else                 ((float*)embOutU_)[r] = v;
        float rc_u = __builtin_amdgcn_rcpf(fmaxf(c_u, 1.f));
        meanI[r] = (_Float16)(s_i * rc_i);
        redI[r]  = (_Float16)m_if;
        meanU[r] = (_Float16)(s_u * rc_u);
        redU[r]  = m_u;
    } else {
        size_t r = (size_t)(h - NU) * 64 + lane;
        if constexpr (OUT16) ((_Float16*)embOutE_)[r] = (_Float16)v;
        else                 ((float*)embOutE_)[r] = v;
        meanE[r] = (_Float16)(s_i * rc_i);
        redE[r]  = (_Float16)m_if;
    }
}

// ---------------- fused finalize (swapped MFMA, zero LDS): user then ent blocks ----------
template<bool OUT16>
__global__ __launch_bounds__(256) void fin_pass(
    const _Float16* __restrict__ meanI, const _Float16* __restrict__ redI,
    const _Float16* __restrict__ meanU, const _Float16* __restrict__ redU,
    const _Float16* __restrict__ meanE, const _Float16* __restrict__ redE,
    const _Float16* __restrict__ oW1f, const float* __restrict__ ob1,
    const _Float16* __restrict__ oW2f, const float* __restrict__ ob2,
    void* __restrict__ outOffU_, void* __restrict__ entOff_)
{
    int lane = threadIdx.x & 63, wid = threadIdx.x >> 6;
    int lr = lane & 15, lk = lane >> 4;

    if (blockIdx.x >= UFIN_BLKS) {
        int n0 = (((int)blockIdx.x - UFIN_BLKS) * 4 + wid) * 16;
        if (n0 >= NENT) return;
        f16x4 am[4];
        #pragma unroll
        for (int ks = 0; ks < 4; ++ks) am[ks] = *(const f16x4*)(meanE + (size_t)(n0 + lr) * 64 + ks * 16 + lk * 4);
        #pragma unroll
        for (int dt = 0; dt < 4; ++dt) {
            f32x4 c = bias4(ob2, dt, lk);
            #pragma unroll
            for (int ks = 0; ks < 4; ++ks) c = mmw(fragp(oW2f, dt, ks, lane), am[ks], c);
            size_t idx = (size_t)(n0 + lr) * 64 + dt * 16 + lk * 4;
            f16x4 red = *(const f16x4*)(redE + idx);
            if constexpr (OUT16) {
                f16x4 o;
                #pragma unroll
                for (int r = 0; r < 4; ++r) o[r] = (_Float16)((float)red[r] * sigmoid_f(c[r]));
                *(f16x4*)((_Float16*)entOff_ + idx) = o;
            } else {
                float4 o;
                float* po = &o.x;
                #pragma unroll
                for (int r = 0; r < 4; ++r) po[r] = (float)red[r] * sigmoid_f(c[r]);
                *(float4*)((float*)entOff_ + idx) = o;
            }
        }
        return;
    }

    int u0 = (blockIdx.x * 4 + wid) * 16;
    if (u0 >= NU) return;

    f16x4 W1f[4][4], W2f[4][4];
    #pragma unroll
    for (int dt = 0; dt < 4; ++dt)
        #pragma unroll
        for (int ks = 0; ks < 4; ++ks) {
            W1f[dt][ks] = fragp(oW1f, dt, ks, lane);
            W2f[dt][ks] = fragp(oW2f, dt, ks, lane);
        }

    f16x4 am[4];
    f32x4 iu[4], uu[4];
    #pragma unroll
    for (int ks = 0; ks < 4; ++ks) am[ks] = *(const f16x4*)(meanI + (size_t)(u0 + lr) * 64 + ks * 16 + lk * 4);
    #pragma unroll
    for (int dt = 0; dt < 4; ++dt) {
        f32x4 c = bias4(ob2, dt, lk);
        #pragma unroll
        for (int ks = 0; ks < 4; ++ks) c = mmw(W2f[dt][ks], am[ks], c);
        f16x4 red = *(const f16x4*)(redI + (size_t)(u0 + lr) * 64 + dt * 16 + lk * 4);
        #pragma unroll
        for (int r = 0; r < 4; ++r) iu[dt][r] = (float)red[r] * sigmoid_f(c[r]);
    }
    #pragma unroll
    for (int ks = 0; ks < 4; ++ks) am[ks] = *(const f16x4*)(meanU + (size_t)(u0 + lr) * 64 + ks * 16 + lk * 4);
    #pragma unroll
    for (int dt = 0; dt < 4; ++dt) {
        f32x4 c = bias4(ob2, dt, lk);
        #pragma unroll
        for (int ks = 0; ks < 4; ++ks) c = mmw(W2f[dt][ks], am[ks], c);
        f16x4 red = *(const f16x4*)(redU + (size_t)(u0 + lr) * 64 + dt * 16 + lk * 4);
        #pragma unroll
        for (int r = 0; r < 4; ++r) uu[dt][r] = (float)red[r] * sigmoid_f(c[r]);
    }
    f16x4 iuf[4], uuf[4];
    #pragma unroll
    for (int ks = 0; ks < 4; ++ks)
        #pragma unroll
        for (int r = 0; r < 4; ++r) { iuf[ks][r] = (_Float16)iu[ks][r]; uuf[ks][r] = (_Float16)uu[ks][r]; }
    f32x4 mn[4];
    #pragma unroll
    for (int dt = 0; dt < 4; ++dt) {
        f32x4 c = bias4(ob1, dt, lk);
        #pragma unroll
        for (int ks = 0; ks < 4; ++ks) c = mmw(W1f[dt][ks], iuf[ks], c);
        #pragma unroll
        for (int r = 0; r < 4; ++r) mn[dt][r] = fmaxf(c[r], 0.f);
    }
    #pragma unroll
    for (int dt = 0; dt < 4; ++dt) {
        f32x4 c = bias4(ob1, dt, lk);
        #pragma unroll
        for (int ks = 0; ks < 4; ++ks) c = mmw(W1f[dt][ks], uuf[ks], c);
        #pragma unroll
        for (int r = 0; r < 4; ++r) mn[dt][r] = 0.5f * (mn[dt][r] + fmaxf(c[r], 0.f));
    }
    f16x4 mnf[4];
    #pragma unroll
    for (int ks = 0; ks < 4; ++ks)
        #pragma unroll
        for (int r = 0; r < 4; ++r) mnf[ks][r] = (_Float16)mn[ks][r];
    #pragma unroll
    for (int dt = 0; dt < 4; ++dt) {
        f32x4 c = bias4(ob2, dt, lk);
        #pragma unroll
        for (int ks = 0; ks < 4; ++ks) c = mmw(W2f[dt][ks], mnf[ks], c);
        size_t idx = (size_t)(u0 + lr) * 64 + dt * 16 + lk * 4;
        if constexpr (OUT16) {
            f16x4 o;
            #pragma unroll
            for (int r = 0; r < 4; ++r)
                o[r] = (_Float16)fmaxf(fmaxf(iu[dt][r], uu[dt][r]) * sigmoid_f(c[r]), 0.f);
            *(f16x4*)((_Float16*)outOffU_ + idx) = o;
        } else {
            float4 o;
            float* po = &o.x;
            #pragma unroll
            for (int r = 0; r < 4; ++r)
                po[r] = fmaxf(fmaxf(iu[dt][r], uu[dt][r]) * sigmoid_f(c[r]), 0.f);
            *(float4*)((float*)outOffU_ + idx) = o;
        }
    }
}

extern "C" void kernel_launch(void* const* d_in, const int* in_sizes, int n_in,
                              void* d_out, int out_size, void* d_ws, size_t ws_size,
                              hipStream_t stream)
{
    const float* user_emb = (const float*)d_in[0];
    const float* user_off = (const float*)d_in[1];
    const float* item_emb = (const float*)d_in[2];
    const float* item_off = (const float*)d_in[3];
    const float* cW1 = (const float*)d_in[4];
    const float* cb1 = (const float*)d_in[5];
    const float* cW2 = (const float*)d_in[6];
    const float* cb2 = (const float*)d_in[7];
    const float* oW1 = (const float*)d_in[8];
    const float* ob1 = (const float*)d_in[9];
    const float* oW2 = (const float*)d_in[10];
    const float* ob2 = (const float*)d_in[11];
    const int* head = (const int*)d_in[12];
    const int* tail = (const int*)d_in[13];
    float* out = (float*)d_out;

    const size_t SZ = (size_t)NN * 64;
    // budget ≈ 54.4M float-equiv < 65.3M proven in R7/R8
    _Float16* A16   = (_Float16*)d_ws;             // layer-0 emb out [NN,64] f16
    _Float16* B16   = A16 + SZ;                    // layer-0 off out [NN,64] f16
    unsigned* packedA = (unsigned*)(B16 + SZ);     // [NN,64] {EV,P} f16 pairs
    unsigned* packedB = packedA + SZ;              // [NN,64] {AO,OFF} f16 pairs
    _Float16* meanI_h = (_Float16*)(packedB + SZ); // [NU,64] f16
    _Float16* redI_h  = meanI_h + (size_t)NU * 64;
    _Float16* meanU_h = redI_h + (size_t)NU * 64;
    _Float16* redU_h  = meanU_h + (size_t)NU * 64;
    _Float16* meanE_h = redU_h + (size_t)NU * 64;  // [NENT,64] f16
    _Float16* redE_h  = meanE_h + (size_t)NENT * 64;
    _Float16* wpre    = redE_h + (size_t)NENT * 64; // 4 * 4096 f16 frag-linear tables
    int* counts   = (int*)(wpre + 4 * 4096);       // NB
    int* offsets  = counts + NB;               // NB+1
    int* cursor   = offsets + NB + 1;          // NB
    int* sorted_t = cursor + NB;               // NEDGE (pre-shifted tail<<8)
    int* partials = sorted_t + NEDGE;          // SCAN_NB
    int* carries  = partials + SCAN_NB;        // SCAN_NB

    const _Float16* cW1f = wpre;
    const _Float16* cW2f = wpre + 4096;
    const _Float16* oW1f = wpre + 8192;
    const _Float16* oW2f = wpre + 12288;

    // weight prepack + counts zero, then class-partitioned CSR build
    prep_zero<<<64 + (NB + 255) / 256, 256, 0, stream>>>(cW1, cW2, oW1, oW2,
                                                         (_Float16*)wpre, counts);
    hist_k<<<(NEDGE + 255) / 256, 256, 0, stream>>>(head, tail, counts);
    scan_local<<<SCAN_NB, 1024, 0, stream>>>(counts, offsets, partials);
    scan_carry<<<1, 1024, 0, stream>>>(partials, carries);
    scan_add<<<SCAN_NB, 1024, 0, stream>>>(offsets, carries, cursor);
    scatter_k<<<(NEDGE + 255) / 256, 256, 0, stream>>>(head, tail, cursor, sorted_t);

    // ---- layer 0: f32 inputs -> f16 A/B ----
    node_pass<float><<<NODE_BLKS, 256, 0, stream>>>(
        user_emb, item_emb, user_off, item_off,
        cW1f, cb1, cW2f, cb2, oW1f, ob1, packedA, packedB);
    seg_pass<true><<<NN / 4, 256, 0, stream>>>(
        packedA, packedB, offsets, sorted_t,
        A16, A16 + (size_t)NU * 64,
        meanI_h, redI_h, meanU_h, redU_h, meanE_h, redE_h);
    fin_pass<true><<<UFIN_BLKS + EFIN_BLKS, 256, 0, stream>>>(
        meanI_h, redI_h, meanU_h, redU_h, meanE_h, redE_h,
        oW1f, ob1, oW2f, ob2, B16, B16 + (size_t)NU * 64);

    // ---- layer 1: f16 inputs -> f32 outputs in d_out ----
    node_pass<_Float16><<<NODE_BLKS, 256, 0, stream>>>(
        A16, A16 + (size_t)NU * 64, B16, B16 + (size_t)NU * 64,
        cW1f, cb1, cW2f, cb2, oW1f, ob1, packedA, packedB);
    seg_pass<false><<<NN / 4, 256, 0, stream>>>(
        packedA, packedB, offsets, sorted_t,
        out, out + (size_t)2 * NU * 64,
        meanI_h, redI_h, meanU_h, redU_h, meanE_h, redE_h);
    fin_pass<false><<<UFIN_BLKS + EFIN_BLKS, 256, 0, stream>>>(
        meanI_h, redI_h, meanU_h, redU_h, meanE_h, redE_h,
        oW1f, ob1, oW2f, ob2, out + (size_t)NU * 64, out + ((size_t)2 * NU + NENT) * 64);
}

// Round 16
// 403.581 us; speedup vs baseline: 1.0524x; 1.0524x over previous
//
#include <hip/hip_runtime.h>
#include <hip/hip_fp16.h>
#include <math.h>

#define NU 100000
#define NI 50000
#define NENT 80000
#define NN 180000
#define NEDGE 800000
#define SCAN_NB ((NN + 1023) / 1024)   // 176
#define UFIN_BLKS ((NU + 63) / 64)     // 1563
#define EFIN_BLKS (NENT / 64)          // 1250
#define NODE_BLKS ((NN / 16 + 3) / 4)  // 2813

typedef _Float16 f16x4 __attribute__((ext_vector_type(4)));
typedef _Float16 f16x2 __attribute__((ext_vector_type(2)));
typedef float f32x4 __attribute__((ext_vector_type(4)));

__device__ __forceinline__ float sigmoid_f(float x) { return 1.0f / (1.0f + __expf(-x)); }
__device__ __forceinline__ unsigned pack2(float a, float b) {
    __half2 h = __floats2half2_rn(a, b);
    return *(unsigned*)&h;
}
__device__ __forceinline__ f16x2 u2h2(unsigned u) { union { unsigned u; f16x2 h; } x; x.u = u; return x.h; }
__device__ __forceinline__ float fdot2f(f16x2 a, f16x2 b, float c) {
#if __has_builtin(__builtin_amdgcn_fdot2)
    return __builtin_amdgcn_fdot2(a, b, c, false);
#else
    return (float)a[0] * (float)b[0] + (float)a[1] * (float)b[1] + c;
#endif
}
__device__ __forceinline__ _Float16 hminf(_Float16 a, _Float16 b) { return a < b ? a : b; }
__device__ __forceinline__ _Float16 hmaxf(_Float16 a, _Float16 b) { return a > b ? a : b; }

// frag load (f32: convert; f16: direct)
template<typename T>
__device__ __forceinline__ f16x4 ldfrag(const T* __restrict__ p) {
    if constexpr (sizeof(T) == 2) {
        return *(const f16x4*)p;
    } else {
        float4 v = *(const float4*)p;
        f16x4 r; r[0] = (_Float16)v.x; r[1] = (_Float16)v.y; r[2] = (_Float16)v.z; r[3] = (_Float16)v.w;
        return r;
    }
}
template<typename T>
__device__ __forceinline__ f16x4 ldfragr(const T* __restrict__ p) {   // relu before/after cvt
    if constexpr (sizeof(T) == 2) {
        f16x4 v = *(const f16x4*)p;
        #pragma unroll
        for (int i = 0; i < 4; ++i) v[i] = hmaxf(v[i], (_Float16)0.f);
        return v;
    } else {
        float4 v = *(const float4*)p;
        f16x4 r;
        r[0] = (_Float16)fmaxf(v.x, 0.f); r[1] = (_Float16)fmaxf(v.y, 0.f);
        r[2] = (_Float16)fmaxf(v.z, 0.f); r[3] = (_Float16)fmaxf(v.w, 0.f);
        return r;
    }
}
// prepacked weight frag: coalesced 8B/lane from an L1-resident 8KB table
__device__ __forceinline__ f16x4 fragp(const _Float16* __restrict__ Wp, int dt, int ks, int lane) {
    return *(const f16x4*)(Wp + (((dt * 4 + ks) * 64 + lane) << 2));
}
__device__ __forceinline__ f32x4 mm(f16x4 a, f16x4 b, f32x4 c) {
    return __builtin_amdgcn_mfma_f32_16x16x16f16(a, b, c, 0, 0, 0);
}

// ---------------- weight prepack: f32 row-major -> frag-linear f16 ----------------
__global__ __launch_bounds__(256) void prep_w(
    const float* __restrict__ W0, const float* __restrict__ W1,
    const float* __restrict__ W2, const float* __restrict__ W3,
    _Float16* __restrict__ out)
{
    int idx = blockIdx.x * 256 + threadIdx.x;          // 0 .. 16383
    int mat = idx >> 12, wi = idx & 4095;
    const float* W = (mat == 0) ? W0 : (mat == 1) ? W1 : (mat == 2) ? W2 : W3;
    int tile = wi >> 8;            // dt*4+ks
    int dt = tile >> 2, ks = tile & 3;
    int ln = (wi >> 2) & 63, j = wi & 3;
    int lr = ln & 15, lk = ln >> 4;
    out[idx] = (_Float16)W[(size_t)(dt * 16 + lr) * 64 + ks * 16 + lk * 4 + j];
}

// ---------------- node pass: 16 nodes/wave via MFMA; writes split f16 pairs ----------------
template<typename T>
__global__ __launch_bounds__(256) void node_pass(
    const T* __restrict__ embU, const T* __restrict__ embE,
    const T* __restrict__ offU, const T* __restrict__ offE,
    const _Float16* __restrict__ cW1f, const float* __restrict__ cb1,
    const _Float16* __restrict__ cW2f, const float* __restrict__ cb2,
    const _Float16* __restrict__ oW1f, const float* __restrict__ ob1,
    unsigned* __restrict__ packedA, unsigned* __restrict__ packedB)
{
    __shared__ _Float16 tb[4][16 * 72];   // per-wave transpose tile, +8 f16 pad
    int lane = threadIdx.x & 63, wid = threadIdx.x >> 6;
    int n0 = (blockIdx.x * 4 + wid) * 16;
    if (n0 >= NN) return;
    int lr = lane & 15, lk = lane >> 4;
    const T* eb; const T* ob;
    if (n0 < NU) { eb = embU + (size_t)n0 * 64; ob = offU + (size_t)n0 * 64; }
    else         { eb = embE + (size_t)(n0 - NU) * 64; ob = offE + (size_t)(n0 - NU) * 64; }

    // ---- center net: a1 = relu(W1 x + b1) ----
    f16x4 ax[4];
    #pragma unroll
    for (int ks = 0; ks < 4; ++ks) ax[ks] = ldfrag(eb + (size_t)lr * 64 + ks * 16 + lk * 4);
    f32x4 acc[4];
    #pragma unroll
    for (int dt = 0; dt < 4; ++dt) {
        float b = cb1[dt * 16 + lr];
        f32x4 c = {b, b, b, b};
        #pragma unroll
        for (int ks = 0; ks < 4; ++ks) c = mm(ax[ks], fragp(cW1f, dt, ks, lane), c);
        acc[dt] = c;
    }
    _Float16* T16 = tb[wid];
    #pragma unroll
    for (int dt = 0; dt < 4; ++dt)
        #pragma unroll
        for (int r = 0; r < 4; ++r)
            T16[(lk * 4 + r) * 72 + dt * 16 + lr] = (_Float16)fmaxf(acc[dt][r], 0.f);
    f16x4 a1[4];
    #pragma unroll
    for (int ks = 0; ks < 4; ++ks) a1[ks] = *(const f16x4*)(T16 + lr * 72 + ks * 16 + lk * 4);
    #pragma unroll
    for (int dt = 0; dt < 4; ++dt) {
        float b = cb2[dt * 16 + lr];
        f32x4 c = {b, b, b, b};
        #pragma unroll
        for (int ks = 0; ks < 4; ++ks) c = mm(a1[ks], fragp(cW2f, dt, ks, lane), c);
        acc[dt] = c;
    }
    // ---- offset net: ao = relu(O1 relu(o) + ob1) ----
    f16x4 axo[4];
    #pragma unroll
    for (int ks = 0; ks < 4; ++ks) axo[ks] = ldfragr(ob + (size_t)lr * 64 + ks * 16 + lk * 4);
    f32x4 acco[4];
    #pragma unroll
    for (int dt = 0; dt < 4; ++dt) {
        float b = ob1[dt * 16 + lr];
        f32x4 c = {b, b, b, b};
        #pragma unroll
        for (int ks = 0; ks < 4; ++ks) c = mm(axo[ks], fragp(oW1f, dt, ks, lane), c);
        acco[dt] = c;
    }
    // ---- transpose x to D-layout via T (wave-private sequential reuse; no barrier) ----
    #pragma unroll
    for (int ks = 0; ks < 4; ++ks) *(f16x4*)(T16 + lr * 72 + ks * 16 + lk * 4) = ax[ks];
    _Float16 xv[16];
    #pragma unroll
    for (int dt = 0; dt < 4; ++dt)
        #pragma unroll
        for (int r = 0; r < 4; ++r) xv[dt * 4 + r] = T16[(lk * 4 + r) * 72 + dt * 16 + lr];
    // ---- transpose relu(o) similarly ----
    #pragma unroll
    for (int ks = 0; ks < 4; ++ks) *(f16x4*)(T16 + lr * 72 + ks * 16 + lk * 4) = axo[ks];
    #pragma unroll
    for (int dt = 0; dt < 4; ++dt) {
        #pragma unroll
        for (int r = 0; r < 4; ++r) {
            int li = lk * 4 + r;
            float ev = __expf(acc[dt][r]);   // segment-max shift skipped: |lg| << 1
            float xf = (float)xv[dt * 4 + r];
            float ovf = (float)T16[(lk * 4 + r) * 72 + dt * 16 + lr];
            float aov = fmaxf(acco[dt][r], 0.f);
            size_t idx = (size_t)(n0 + li) * 64 + dt * 16 + lr;
            packedA[idx] = pack2(ev, ev * xf);
            packedB[idx] = pack2(aov, ovf);
        }
    }
}

// ---------------- CSR build ----------------
__global__ __launch_bounds__(256) void hist_k(const int* __restrict__ head, int* __restrict__ counts) {
    int e = blockIdx.x * 256 + threadIdx.x;
    if (e < NEDGE) atomicAdd(&counts[head[e]], 1);
}

__global__ __launch_bounds__(1024) void scan_local(const int* __restrict__ counts,
                                                   int* __restrict__ excl, int* __restrict__ partials) {
    __shared__ int wsum[16];
    int tid = threadIdx.x, lane = tid & 63, wid = tid >> 6;
    int i = blockIdx.x * 1024 + tid;
    int v = (i < NN) ? counts[i] : 0;
    int s = v;
    #pragma unroll
    for (int d = 1; d < 64; d <<= 1) { int u = __shfl_up(s, d, 64); if (lane >= d) s += u; }
    if (lane == 63) wsum[wid] = s;
    __syncthreads();
    if (wid == 0 && lane < 16) {
        int w = wsum[lane];
        #pragma unroll
        for (int d = 1; d < 16; d <<= 1) { int u = __shfl_up(w, d, 64); if (lane >= d) w += u; }
        wsum[lane] = w;
    }
    __syncthreads();
    int base = wid ? wsum[wid - 1] : 0;
    if (i < NN) excl[i] = base + s - v;
    if (tid == 1023) partials[blockIdx.x] = wsum[15];
}

__global__ __launch_bounds__(256) void scan_carry(const int* __restrict__ partials, int* __restrict__ carries) {
    __shared__ int ws[4];
    int tid = threadIdx.x, lane = tid & 63, wid = tid >> 6;
    int v = (tid < SCAN_NB) ? partials[tid] : 0;
    int s = v;
    #pragma unroll
    for (int d = 1; d < 64; d <<= 1) { int u = __shfl_up(s, d, 64); if (lane >= d) s += u; }
    if (lane == 63) ws[wid] = s;
    __syncthreads();
    int add = 0;
    for (int w = 0; w < wid; ++w) add += ws[w];
    if (tid < SCAN_NB) carries[tid] = add + s - v;
}

__global__ __launch_bounds__(1024) void scan_add(int* __restrict__ excl, const int* __restrict__ carries,
                                                 int* __restrict__ cursor) {
    int i = blockIdx.x * 1024 + threadIdx.x;
    if (i < NN) { int o = excl[i] + carries[blockIdx.x]; excl[i] = o; cursor[i] = o; }
    if (i == 0) excl[NN] = NEDGE;
}

__global__ __launch_bounds__(256) void scatter_k(const int* __restrict__ head, const int* __restrict__ tail,
                                                 int* __restrict__ cursor, int* __restrict__ sorted_t) {
    int e = blockIdx.x * 256 + threadIdx.x;
    if (e < NEDGE) { int pos = atomicAdd(&cursor[head[e]], 1); sorted_t[pos] = tail[e]; }
}

// ---------------- segment pass: one wave per head; move-free 2-slot pipeline ----------------
template<bool OUT16>
__global__ __launch_bounds__(256) void seg_pass(
    const unsigned* __restrict__ packedA, const unsigned* __restrict__ packedB,
    const int* __restrict__ offsets, const int* __restrict__ sorted_t,
    void* __restrict__ embOutU_, void* __restrict__ embOutE_,
    _Float16* __restrict__ meanI, _Float16* __restrict__ redI,
    _Float16* __restrict__ meanU, _Float16* __restrict__ redU,
    _Float16* __restrict__ meanE, _Float16* __restrict__ redE)
{
    int lane = threadIdx.x & 63;
    int h = blockIdx.x * 4 + (threadIdx.x >> 6);    // NN % 4 == 0
    int beg = offsets[h], end = offsets[h + 1];
    bool isUser = (h < NU);
    bool entMin = (h >= NU + NI);
    const f16x2 SEL_LO = {(_Float16)1.0f, (_Float16)0.0f};
    const f16x2 SEL_HI = {(_Float16)0.0f, (_Float16)1.0f};
    float num = 0.f, den = 0.f, s_i = 0.f, s_u = 0.f;
    const _Float16 HINF = u2h2(0x7C007C00u)[0];
    _Float16 m_i = (isUser || entMin) ? HINF : (_Float16)0.f;   // min classes start at +inf
    _Float16 m_u = (_Float16)0.f;
    int c_i = 0, c_u = 0;

    const char* pA = (const char*)packedA;
    const char* pB = (const char*)packedB;
    int loff = lane << 2;

#define LOADQ(t, a, b)                                                          \
    do {                                                                        \
        a = *(const unsigned*)(pA + ((size_t)(unsigned)(t) << 8) + loff);       \
        if (!isUser || (t) >= NU)                                               \
            b = *(const unsigned*)(pB + ((size_t)(unsigned)(t) << 8) + loff);   \
    } while (0)

#define CONSUME(tc, qa, qb)                                                     \
    do {                                                                        \
        f16x2 ea = u2h2(qa);                                                    \
        den = fdot2f(ea, SEL_LO, den);                                          \
        num = fdot2f(ea, SEL_HI, num);                                          \
        if (isUser) {                                                           \
            if ((tc) >= NU) {                                                   \
                f16x2 ab = u2h2(qb);                                            \
                if ((tc) < NU + NI) { s_i = fdot2f(ab, SEL_LO, s_i); m_i = hminf(m_i, ab[1]); c_i++; } \
                else                { s_u = fdot2f(ab, SEL_LO, s_u); m_u = hmaxf(m_u, ab[1]); c_u++; } \
            }                                                                   \
        } else {                                                                \
            f16x2 ab = u2h2(qb);                                                \
            s_i = fdot2f(ab, SEL_LO, s_i); c_i++;                               \
            m_i = entMin ? hminf(m_i, ab[1]) : hmaxf(m_i, ab[1]);               \
        }                                                                       \
    } while (0)

    for (int base = beg; base < end; base += 64) {
        int rem = end - base; if (rem > 64) rem = 64;
        int tv = sorted_t[base + (lane < rem ? lane : 0)];
        // two slots, consumed then reloaded in place: no register rotation moves
        int tA = 0, tB = 0; unsigned aA = 0, aB = 0, bA = 0, bB = 0;
        tA = __builtin_amdgcn_readlane(tv, 0);
        LOADQ(tA, aA, bA);
        if (rem > 1) { tB = __builtin_amdgcn_readlane(tv, 1); LOADQ(tB, aB, bB); }
        int j = 0;
        for (; j + 2 <= rem; j += 2) {
            CONSUME(tA, aA, bA);
            if (j + 2 < rem) { tA = __builtin_amdgcn_readlane(tv, j + 2); LOADQ(tA, aA, bA); }
            CONSUME(tB, aB, bB);
            if (j + 3 < rem) { tB = __builtin_amdgcn_readlane(tv, j + 3); LOADQ(tB, aB, bB); }
        }
        if (j < rem) CONSUME(tA, aA, bA);   // odd tail
    }
#undef LOADQ
#undef CONSUME

    // center: softmax-weighted mean + row L2 normalize
    float v = (den > 0.f) ? num / den : 0.f;
    float sq = v * v;
    #pragma unroll
    for (int m = 32; m; m >>= 1) sq += __shfl_xor(sq, m, 64);
    v = v / fmaxf(sqrtf(sq), 1e-12f);

    float m_if = (float)m_i;
    if (m_if > 1e37f) m_if = 0.f;                   // empty min-segment -> 0
    float rc_i = __builtin_amdgcn_rcpf(fmaxf((float)c_i, 1.f));
    if (isUser) {
        size_t r = (size_t)h * 64 + lane;
        if constexpr (OUT16) ((_Float16*)embOutU_)[r] = (_Float16)v;
        else                 ((float*)embOutU_)[r] = v;
        float rc_u = __builtin_amdgcn_rcpf(fmaxf((float)c_u, 1.f));
        meanI[r] = (_Float16)(s_i * rc_i);
        redI[r]  = (_Float16)m_if;
        meanU[r] = (_Float16)(s_u * rc_u);
        redU[r]  = m_u;
    } else {
        size_t r = (size_t)(h - NU) * 64 + lane;
        if constexpr (OUT16) ((_Float16*)embOutE_)[r] = (_Float16)v;
        else                 ((float*)embOutE_)[r] = v;
        meanE[r] = (_Float16)(s_i * rc_i);
        redE[r]  = (_Float16)m_if;
    }
}

// ---------------- fused finalize: user blocks then ent blocks ----------------
template<bool OUT16>
__global__ __launch_bounds__(256) void fin_pass(
    const _Float16* __restrict__ meanI, const _Float16* __restrict__ redI,
    const _Float16* __restrict__ meanU, const _Float16* __restrict__ redU,
    const _Float16* __restrict__ meanE, const _Float16* __restrict__ redE,
    const _Float16* __restrict__ oW1f, const float* __restrict__ ob1,
    const _Float16* __restrict__ oW2f, const float* __restrict__ ob2,
    void* __restrict__ outOffU_, void* __restrict__ entOff_)
{
    int lane = threadIdx.x & 63, wid = threadIdx.x >> 6;
    int lr = lane & 15, lk = lane >> 4;

    if (blockIdx.x >= UFIN_BLKS) {
        // ---- ent part: gate matvec only ----
        int n0 = (((int)blockIdx.x - UFIN_BLKS) * 4 + wid) * 16;
        if (n0 >= NENT) return;
        f16x4 am[4];
        #pragma unroll
        for (int ks = 0; ks < 4; ++ks) am[ks] = *(const f16x4*)(meanE + (size_t)(n0 + lr) * 64 + ks * 16 + lk * 4);
        #pragma unroll
        for (int dt = 0; dt < 4; ++dt) {
            float b = ob2[dt * 16 + lr];
            f32x4 c = {b, b, b, b};
            #pragma unroll
            for (int ks = 0; ks < 4; ++ks) c = mm(am[ks], fragp(oW2f, dt, ks, lane), c);
            #pragma unroll
            for (int r = 0; r < 4; ++r) {
                size_t row = (size_t)(n0 + lk * 4 + r);
                float val = (float)redE[row * 64 + dt * 16 + lr] * sigmoid_f(c[r]);
                if constexpr (OUT16) ((_Float16*)entOff_)[row * 64 + dt * 16 + lr] = (_Float16)val;
                else                 ((float*)entOff_)[row * 64 + dt * 16 + lr] = val;
            }
        }
        return;
    }

    // ---- user part: fused 2-level offset net ----
    __shared__ _Float16 tb[4][16 * 72];
    int u0 = (blockIdx.x * 4 + wid) * 16;
    if (u0 >= NU) return;
    _Float16* T16 = tb[wid];

    f16x4 W1f[4][4], W2f[4][4];
    float b1d[4], b2d[4];
    #pragma unroll
    for (int dt = 0; dt < 4; ++dt) {
        b1d[dt] = ob1[dt * 16 + lr]; b2d[dt] = ob2[dt * 16 + lr];
        #pragma unroll
        for (int ks = 0; ks < 4; ++ks) {
            W1f[dt][ks] = fragp(oW1f, dt, ks, lane);
            W2f[dt][ks] = fragp(oW2f, dt, ks, lane);
        }
    }

    f16x4 am[4];
    f32x4 iu[4], uu[4];
    #pragma unroll
    for (int ks = 0; ks < 4; ++ks) am[ks] = *(const f16x4*)(meanI + (size_t)(u0 + lr) * 64 + ks * 16 + lk * 4);
    #pragma unroll
    for (int dt = 0; dt < 4; ++dt) {
        f32x4 c = {b2d[dt], b2d[dt], b2d[dt], b2d[dt]};
        #pragma unroll
        for (int ks = 0; ks < 4; ++ks) c = mm(am[ks], W2f[dt][ks], c);
        #pragma unroll
        for (int r = 0; r < 4; ++r)
            iu[dt][r] = (float)redI[(size_t)(u0 + lk * 4 + r) * 64 + dt * 16 + lr] * sigmoid_f(c[r]);
    }
    #pragma unroll
    for (int ks = 0; ks < 4; ++ks) am[ks] = *(const f16x4*)(meanU + (size_t)(u0 + lr) * 64 + ks * 16 + lk * 4);
    #pragma unroll
    for (int dt = 0; dt < 4; ++dt) {
        f32x4 c = {b2d[dt], b2d[dt], b2d[dt], b2d[dt]};
        #pragma unroll
        for (int ks = 0; ks < 4; ++ks) c = mm(am[ks], W2f[dt][ks], c);
        #pragma unroll
        for (int r = 0; r < 4; ++r)
            uu[dt][r] = (float)redU[(size_t)(u0 + lk * 4 + r) * 64 + dt * 16 + lr] * sigmoid_f(c[r]);
    }
    #pragma unroll
    for (int dt = 0; dt < 4; ++dt)
        #pragma unroll
        for (int r = 0; r < 4; ++r) T16[(lk * 4 + r) * 72 + dt * 16 + lr] = (_Float16)iu[dt][r];
    #pragma unroll
    for (int ks = 0; ks < 4; ++ks) am[ks] = *(const f16x4*)(T16 + lr * 72 + ks * 16 + lk * 4);
    f32x4 mn[4];
    #pragma unroll
    for (int dt = 0; dt < 4; ++dt) {
        f32x4 c = {b1d[dt], b1d[dt], b1d[dt], b1d[dt]};
        #pragma unroll
        for (int ks = 0; ks < 4; ++ks) c = mm(am[ks], W1f[dt][ks], c);
        #pragma unroll
        for (int r = 0; r < 4; ++r) mn[dt][r] = fmaxf(c[r], 0.f);
    }
    #pragma unroll
    for (int dt = 0; dt < 4; ++dt)
        #pragma unroll
        for (int r = 0; r < 4; ++r) T16[(lk * 4 + r) * 72 + dt * 16 + lr] = (_Float16)uu[dt][r];
    #pragma unroll
    for (int ks = 0; ks < 4; ++ks) am[ks] = *(const f16x4*)(T16 + lr * 72 + ks * 16 + lk * 4);
    #pragma unroll
    for (int dt = 0; dt < 4; ++dt) {
        f32x4 c = {b1d[dt], b1d[dt], b1d[dt], b1d[dt]};
        #pragma unroll
        for (int ks = 0; ks < 4; ++ks) c = mm(am[ks], W1f[dt][ks], c);
        #pragma unroll
        for (int r = 0; r < 4; ++r) mn[dt][r] = 0.5f * (mn[dt][r] + fmaxf(c[r], 0.f));
    }
    #pragma unroll
    for (int dt = 0; dt < 4; ++dt)
        #pragma unroll
        for (int r = 0; r < 4; ++r) T16[(lk * 4 + r) * 72 + dt * 16 + lr] = (_Float16)mn[dt][r];
    #pragma unroll
    for (int ks = 0; ks < 4; ++ks) am[ks] = *(const f16x4*)(T16 + lr * 72 + ks * 16 + lk * 4);
    #pragma unroll
    for (int dt = 0; dt < 4; ++dt) {
        f32x4 c = {b2d[dt], b2d[dt], b2d[dt], b2d[dt]};
        #pragma unroll
        for (int ks = 0; ks < 4; ++ks) c = mm(am[ks], W2f[dt][ks], c);
        #pragma unroll
        for (int r = 0; r < 4; ++r) {
            float val = fmaxf(fmaxf(iu[dt][r], uu[dt][r]) * sigmoid_f(c[r]), 0.f);
            size_t idx = (size_t)(u0 + lk * 4 + r) * 64 + dt * 16 + lr;
            if constexpr (OUT16) ((_Float16*)outOffU_)[idx] = (_Float16)val;
            else                 ((float*)outOffU_)[idx] = val;
        }
    }
}

extern "C" void kernel_launch(void* const* d_in, const int* in_sizes, int n_in,
                              void* d_out, int out_size, void* d_ws, size_t ws_size,
                              hipStream_t stream)
{
    const float* user_emb = (const float*)d_in[0];
    const float* user_off = (const float*)d_in[1];
    const float* item_emb = (const float*)d_in[2];
    const float* item_off = (const float*)d_in[3];
    const float* cW1 = (const float*)d_in[4];
    const float* cb1 = (const float*)d_in[5];
    const float* cW2 = (const float*)d_in[6];
    const float* cb2 = (const float*)d_in[7];
    const float* oW1 = (const float*)d_in[8];
    const float* ob1 = (const float*)d_in[9];
    const float* oW2 = (const float*)d_in[10];
    const float* ob2 = (const float*)d_in[11];
    const int* head = (const int*)d_in[12];
    const int* tail = (const int*)d_in[13];
    float* out = (float*)d_out;

    const size_t SZ = (size_t)NN * 64;
    // budget ≈ 53.8M float-equiv < 65.3M proven in R7/R8
    _Float16* A16   = (_Float16*)d_ws;             // layer-0 emb out [NN,64] f16
    _Float16* B16   = A16 + SZ;                    // layer-0 off out [NN,64] f16
    unsigned* packedA = (unsigned*)(B16 + SZ);     // [NN,64] {EV,P} f16 pairs
    unsigned* packedB = packedA + SZ;              // [NN,64] {AO,OFF} f16 pairs
    _Float16* meanI_h = (_Float16*)(packedB + SZ); // [NU,64] f16
    _Float16* redI_h  = meanI_h + (size_t)NU * 64;
    _Float16* meanU_h = redI_h + (size_t)NU * 64;
    _Float16* redU_h  = meanU_h + (size_t)NU * 64;
    _Float16* meanE_h = redU_h + (size_t)NU * 64;  // [NENT,64] f16
    _Float16* redE_h  = meanE_h + (size_t)NENT * 64;
    _Float16* wpre    = redE_h + (size_t)NENT * 64; // 4 * 4096 f16 frag-linear tables
    int* counts   = (int*)(wpre + 4 * 4096);
    int* offsets  = counts + NN;               // NN+1
    int* cursor   = offsets + NN + 1;
    int* sorted_t = cursor + NN;               // NEDGE
    int* partials = sorted_t + NEDGE;          // SCAN_NB
    int* carries  = partials + SCAN_NB;        // SCAN_NB

    const _Float16* cW1f = wpre;
    const _Float16* cW2f = wpre + 4096;
    const _Float16* oW1f = wpre + 8192;
    const _Float16* oW2f = wpre + 12288;

    // weight prepack + CSR build (per call; layer-independent)
    prep_w<<<64, 256, 0, stream>>>(cW1, cW2, oW1, oW2, (_Float16*)wpre);
    hipMemsetAsync(counts, 0, NN * sizeof(int), stream);
    hist_k<<<(NEDGE + 255) / 256, 256, 0, stream>>>(head, counts);
    scan_local<<<SCAN_NB, 1024, 0, stream>>>(counts, offsets, partials);
    scan_carry<<<1, 256, 0, stream>>>(partials, carries);
    scan_add<<<SCAN_NB, 1024, 0, stream>>>(offsets, carries, cursor);
    scatter_k<<<(NEDGE + 255) / 256, 256, 0, stream>>>(head, tail, cursor, sorted_t);

    // ---- layer 0: f32 inputs -> f16 A/B ----
    node_pass<float><<<NODE_BLKS, 256, 0, stream>>>(
        user_emb, item_emb, user_off, item_off,
        cW1f, cb1, cW2f, cb2, oW1f, ob1, packedA, packedB);
    seg_pass<true><<<NN / 4, 256, 0, stream>>>(
        packedA, packedB, offsets, sorted_t,
        A16, A16 + (size_t)NU * 64,
        meanI_h, redI_h, meanU_h, redU_h, meanE_h, redE_h);
    fin_pass<true><<<UFIN_BLKS + EFIN_BLKS, 256, 0, stream>>>(
        meanI_h, redI_h, meanU_h, redU_h, meanE_h, redE_h,
        oW1f, ob1, oW2f, ob2, B16, B16 + (size_t)NU * 64);

    // ---- layer 1: f16 inputs -> f32 outputs in d_out ----
    node_pass<_Float16><<<NODE_BLKS, 256, 0, stream>>>(
        A16, A16 + (size_t)NU * 64, B16, B16 + (size_t)NU * 64,
        cW1f, cb1, cW2f, cb2, oW1f, ob1, packedA, packedB);
    seg_pass<false><<<NN / 4, 256, 0, stream>>>(
        packedA, packedB, offsets, sorted_t,
        out, out + (size_t)2 * NU * 64,
        meanI_h, redI_h, meanU_h, redU_h, meanE_h, redE_h);
    fin_pass<false><<<UFIN_BLKS + EFIN_BLKS, 256, 0, stream>>>(
        meanI_h, redI_h, meanU_h, redU_h, meanE_h, redE_h,
        oW1f, ob1, oW2f, ob2, out + (size_t)NU * 64, out + ((size_t)2 * NU + NENT) * 64);
}